// Round 1
// baseline (34.466 us; speedup 1.0000x reference)
//
#include <hip/hip_runtime.h>

// MapLoss: fused masked-MSE + pos/neg split loss over (32, 512, 512) f32 maps.
//
// Hot-path insight: for the benchmark inputs (gt ~ U[0,1)), n_pos per sample is
// ~0.35-0.4*N >> N/4, so k = min(3*n_pos, n_neg) == n_neg for every row, and the
// hard-negative top-k is exactly "mean over all negatives". n_pos > 0 always, so
// the top-500 fallback never fires. Pass1 therefore only needs per-(sample,map)
// {pos_sum, neg_sum, n_pos}. The general cases (k < n_neg, n_pos == 0) are still
// implemented EXACTLY via serial radix-select in the tiny finalize kernel (never
// exercised on this data, costs nothing on the hot path).

#define NPS (512 * 512)          // elements per sample
#define BPS 64                   // blocks per sample (pass1)
#define EPB 4096                 // elements per block (pass1): 256 thr * 4 iter * 4 f32
#define NB 32                    // batch

constexpr float THR_REGION = 0.6f;
constexpr float THR_AFF    = 0.65f;

// ---------------- pass 1: streaming fused accumulate ----------------
// grid (BPS, NB), block 256. Writes part[b][blk][6] =
// {posSumR, negSumR, cntR, posSumA, negSumA, cntA}. Deterministic (no atomics).
__global__ __launch_bounds__(256) void map_loss_pass1(
    const float* __restrict__ rg, const float* __restrict__ ag,
    const float* __restrict__ rp, const float* __restrict__ ap,
    const float* __restrict__ mk, float* __restrict__ part) {
  const int b   = blockIdx.y;
  const int tid = threadIdx.x;
  const size_t sbase = (size_t)b * NPS + (size_t)blockIdx.x * EPB;

  float v[6] = {0.f, 0.f, 0.f, 0.f, 0.f, 0.f};  // posR negR cntR posA negA cntA

#pragma unroll
  for (int jj = 0; jj < 4; ++jj) {
    const size_t base = sbase + (size_t)jj * 1024 + (size_t)tid * 4;
    const float4 g_r = *reinterpret_cast<const float4*>(rg + base);
    const float4 g_a = *reinterpret_cast<const float4*>(ag + base);
    const float4 p_r = *reinterpret_cast<const float4*>(rp + base);
    const float4 p_a = *reinterpret_cast<const float4*>(ap + base);
    const float4 m_4 = *reinterpret_cast<const float4*>(mk + base);
    const float* gr = reinterpret_cast<const float*>(&g_r);
    const float* ga = reinterpret_cast<const float*>(&g_a);
    const float* pr = reinterpret_cast<const float*>(&p_r);
    const float* pa = reinterpret_cast<const float*>(&p_a);
    const float* mm = reinterpret_cast<const float*>(&m_4);
#pragma unroll
    for (int j = 0; j < 4; ++j) {
      const float m = mm[j];
      // region
      {
        const float g = gr[j];
        float p = pr[j];
        const bool pos = g > THR_REGION;
        if (pos && p > 1.0f) p = 1.0f;
        const float d = p - g;
        const float l = d * d * m;
        if (pos) { v[0] += l; v[2] += 1.0f; } else { v[1] += l; }
      }
      // affinity
      {
        const float g = ga[j];
        float p = pa[j];
        const bool pos = g > THR_AFF;
        if (pos && p > 1.0f) p = 1.0f;
        const float d = p - g;
        const float l = d * d * m;
        if (pos) { v[3] += l; v[5] += 1.0f; } else { v[4] += l; }
      }
    }
  }

  // wave64 shuffle reduce, then cross-wave via LDS
#pragma unroll
  for (int q = 0; q < 6; ++q)
#pragma unroll
    for (int off = 32; off > 0; off >>= 1)
      v[q] += __shfl_down(v[q], off, 64);

  __shared__ float sh[4][6];
  const int lane = tid & 63, wid = tid >> 6;
  if (lane == 0) {
#pragma unroll
    for (int q = 0; q < 6; ++q) sh[wid][q] = v[q];
  }
  __syncthreads();
  if (tid < 6) {
    const float s = sh[0][tid] + sh[1][tid] + sh[2][tid] + sh[3][tid];
    part[((size_t)b * BPS + blockIdx.x) * 6 + tid] = s;
  }
}

// ---------------- exact serial radix-select (rare paths only) ----------------
// Sum of top-k values of the per-element loss map for one (sample,map) row.
// Values are >= 0 (d^2 * mask, mask in [0,1)), so float bit pattern order ==
// value order. 4 passes of 256-bin byte histograms -> exact threshold + ties.
__device__ float topk_sum_row(const float* __restrict__ gt,
                              const float* __restrict__ pd,
                              const float* __restrict__ mm,
                              float thr, int k, bool negOnly) {
  unsigned prefix = 0;
  float sum_def = 0.f;
  int want = k;
  for (int shift = 24; shift >= 0; shift -= 8) {
    unsigned cnt[256];
    float bsum[256];
    for (int i = 0; i < 256; ++i) { cnt[i] = 0; bsum[i] = 0.f; }
    for (int j = 0; j < NPS; ++j) {
      const float g = gt[j];
      const bool pos = g > thr;
      if (negOnly && pos) continue;
      float p = pd[j];
      if (pos && p > 1.0f) p = 1.0f;
      const float d = p - g;
      const float vv = d * d * mm[j];
      const unsigned u = __float_as_uint(vv);
      if (shift < 24 && (u >> (shift + 8)) != (prefix >> (shift + 8))) continue;
      const unsigned bin = (u >> shift) & 255u;
      cnt[bin]++;
      bsum[bin] += vv;
    }
    int bin = 255;
    for (; bin > 0; --bin) {
      if ((int)cnt[bin] < want) { want -= (int)cnt[bin]; sum_def += bsum[bin]; }
      else break;
    }
    prefix |= ((unsigned)bin) << shift;
  }
  sum_def += (float)want * __uint_as_float(prefix);
  return sum_def;
}

// ---------------- pass 2: finalize ----------------
// 1 block x 64 threads; thread t -> (map = t>>5, sample = t&31).
__global__ __launch_bounds__(64) void map_loss_pass2(
    const float* __restrict__ part,
    const float* __restrict__ rg, const float* __restrict__ ag,
    const float* __restrict__ rp, const float* __restrict__ ap,
    const float* __restrict__ mk, float* __restrict__ out) {
  const int t = threadIdx.x;
  const int mapA = t >> 5;  // 0 = region, 1 = affinity
  const int b = t & 31;

  float posSum = 0.f, negSum = 0.f, cntF = 0.f;
  for (int blk = 0; blk < BPS; ++blk) {
    const float* p = part + ((size_t)b * BPS + blk) * 6 + mapA * 3;
    posSum += p[0];
    negSum += p[1];
    cntF   += p[2];
  }

  const int npos = (int)cntF;
  const int nneg = NPS - npos;
  long long k = 3LL * npos;
  if (k > nneg) k = nneg;

  const float thr = mapA ? THR_AFF : THR_REGION;
  const float* gt = (mapA ? ag : rg) + (size_t)b * NPS;
  const float* pd = (mapA ? ap : rp) + (size_t)b * NPS;
  const float* mm = mk + (size_t)b * NPS;

  float per_sample;
  if (npos > 0) {
    const float pos_loss = posSum / (float)npos;
    float neg_loss = 0.f;
    if (k > 0) {
      if (k == (long long)nneg) {
        neg_loss = negSum / (float)nneg;               // hot path: all negatives
      } else {
        neg_loss = topk_sum_row(gt, pd, mm, thr, (int)k, true) / (float)k;
      }
    }
    per_sample = pos_loss + neg_loss;
  } else {
    per_sample = topk_sum_row(gt, pd, mm, thr, 500, false) / 500.0f;
  }

  __shared__ float sh[64];
  sh[t] = per_sample;
  __syncthreads();
  if (t == 0) {
    float char_sum = 0.f, affi_sum = 0.f;
    for (int i = 0; i < 32; ++i) { char_sum += sh[i]; affi_sum += sh[32 + i]; }
    out[0] = 2.0f * char_sum / (float)NB + affi_sum / (float)NB;
  }
}

extern "C" void kernel_launch(void* const* d_in, const int* in_sizes, int n_in,
                              void* d_out, int out_size, void* d_ws, size_t ws_size,
                              hipStream_t stream) {
  const float* rg = (const float*)d_in[0];  // region_score_gt
  const float* ag = (const float*)d_in[1];  // affinity_score_gt
  const float* rp = (const float*)d_in[2];  // region_score_pred
  const float* ap = (const float*)d_in[3];  // affinity_score_pred
  const float* mk = (const float*)d_in[4];  // mask
  float* out = (float*)d_out;
  float* part = (float*)d_ws;  // [NB][BPS][6] f32 = 48 KB, fully rewritten per call

  dim3 grid1(BPS, NB);
  map_loss_pass1<<<grid1, 256, 0, stream>>>(rg, ag, rp, ap, mk, part);
  map_loss_pass2<<<1, 64, 0, stream>>>(part, rg, ag, rp, ap, mk, out);
}

// Round 2
// 32.992 us; speedup vs baseline: 1.0447x; 1.0447x over previous
//
#include <hip/hip_runtime.h>

// MapLoss: fused masked-MSE + pos/neg split loss over (32, 512, 512) f32 maps.
//
// Hot path: for these inputs (gt ~ U[0,1)), n_pos ~ 0.35-0.4*N >> N/4, so
// k = min(3*n_pos, n_neg) == n_neg for every row -> hard-negative top-k is
// exactly "mean over all negatives", and n_pos > 0 always (no top-500
// fallback). Pass1 only needs per-(sample,map) {pos_sum, neg_sum, n_pos}.
// Rare paths (k < n_neg, n_pos == 0) stay exact via serial radix-select in
// pass2 (never exercised on this data; free on the hot path).

#define NPS (512 * 512)          // elements per sample
#define BPS 32                   // blocks per sample (pass1)
#define EPB 8192                 // elements per block: 256 thr * 8 iter * 4 f32
#define NB 32                    // batch

constexpr float THR_REGION = 0.6f;
constexpr float THR_AFF    = 0.65f;

// ---------------- pass 1: streaming fused accumulate ----------------
// grid (BPS, NB) = 1024 blocks, 256 thr. part[b][blk][6] =
// {posSumR, negSumR, cntR, posSumA, negSumA, cntA}. No atomics: deterministic.
__global__ __launch_bounds__(256) void map_loss_pass1(
    const float* __restrict__ rg, const float* __restrict__ ag,
    const float* __restrict__ rp, const float* __restrict__ ap,
    const float* __restrict__ mk, float* __restrict__ part) {
  const int b   = blockIdx.y;
  const int tid = threadIdx.x;
  const size_t sbase = (size_t)b * NPS + (size_t)blockIdx.x * EPB;

  float v[6] = {0.f, 0.f, 0.f, 0.f, 0.f, 0.f};  // posR negR cntR posA negA cntA

#pragma unroll
  for (int jj = 0; jj < 8; ++jj) {
    const size_t base = sbase + (size_t)jj * 1024 + (size_t)tid * 4;
    const float4 g_r = *reinterpret_cast<const float4*>(rg + base);
    const float4 g_a = *reinterpret_cast<const float4*>(ag + base);
    const float4 p_r = *reinterpret_cast<const float4*>(rp + base);
    const float4 p_a = *reinterpret_cast<const float4*>(ap + base);
    const float4 m_4 = *reinterpret_cast<const float4*>(mk + base);
    const float* gr = reinterpret_cast<const float*>(&g_r);
    const float* ga = reinterpret_cast<const float*>(&g_a);
    const float* pr = reinterpret_cast<const float*>(&p_r);
    const float* pa = reinterpret_cast<const float*>(&p_a);
    const float* mm = reinterpret_cast<const float*>(&m_4);
#pragma unroll
    for (int j = 0; j < 4; ++j) {
      const float m = mm[j];
      {  // region
        const float g = gr[j];
        float p = pr[j];
        const bool pos = g > THR_REGION;
        if (pos && p > 1.0f) p = 1.0f;
        const float d = p - g;
        const float l = d * d * m;
        if (pos) { v[0] += l; v[2] += 1.0f; } else { v[1] += l; }
      }
      {  // affinity
        const float g = ga[j];
        float p = pa[j];
        const bool pos = g > THR_AFF;
        if (pos && p > 1.0f) p = 1.0f;
        const float d = p - g;
        const float l = d * d * m;
        if (pos) { v[3] += l; v[5] += 1.0f; } else { v[4] += l; }
      }
    }
  }

  // wave64 shuffle reduce, then cross-wave via LDS
#pragma unroll
  for (int q = 0; q < 6; ++q)
#pragma unroll
    for (int off = 32; off > 0; off >>= 1)
      v[q] += __shfl_down(v[q], off, 64);

  __shared__ float sh[4][6];
  const int lane = tid & 63, wid = tid >> 6;
  if (lane == 0) {
#pragma unroll
    for (int q = 0; q < 6; ++q) sh[wid][q] = v[q];
  }
  __syncthreads();
  if (tid < 6) {
    const float s = sh[0][tid] + sh[1][tid] + sh[2][tid] + sh[3][tid];
    part[((size_t)b * BPS + blockIdx.x) * 6 + tid] = s;
  }
}

// ---------------- exact serial radix-select (rare paths only) ----------------
// Sum of top-k of the per-element loss map for one (sample,map) row. Values are
// >= 0 so float bit order == value order. 4 passes of 256-bin byte histograms.
__device__ float topk_sum_row(const float* __restrict__ gt,
                              const float* __restrict__ pd,
                              const float* __restrict__ mm,
                              float thr, int k, bool negOnly) {
  unsigned prefix = 0;
  float sum_def = 0.f;
  int want = k;
  for (int shift = 24; shift >= 0; shift -= 8) {
    unsigned cnt[256];
    float bsum[256];
    for (int i = 0; i < 256; ++i) { cnt[i] = 0; bsum[i] = 0.f; }
    for (int j = 0; j < NPS; ++j) {
      const float g = gt[j];
      const bool pos = g > thr;
      if (negOnly && pos) continue;
      float p = pd[j];
      if (pos && p > 1.0f) p = 1.0f;
      const float d = p - g;
      const float vv = d * d * mm[j];
      const unsigned u = __float_as_uint(vv);
      if (shift < 24 && (u >> (shift + 8)) != (prefix >> (shift + 8))) continue;
      const unsigned bin = (u >> shift) & 255u;
      cnt[bin]++;
      bsum[bin] += vv;
    }
    int bin = 255;
    for (; bin > 0; --bin) {
      if ((int)cnt[bin] < want) { want -= (int)cnt[bin]; sum_def += bsum[bin]; }
      else break;
    }
    prefix |= ((unsigned)bin) << shift;
  }
  sum_def += (float)want * __uint_as_float(prefix);
  return sum_def;
}

// ---------------- pass 2: parallel finalize ----------------
// 1 block x 256 threads. Row r = (map,sample) handled by 4 lanes; each lane
// sums 8 of the 32 partial-triples, then 2 shfl_xor steps combine the group.
__global__ __launch_bounds__(256) void map_loss_pass2(
    const float* __restrict__ part,
    const float* __restrict__ rg, const float* __restrict__ ag,
    const float* __restrict__ rp, const float* __restrict__ ap,
    const float* __restrict__ mk, float* __restrict__ out) {
  const int t = threadIdx.x;
  const int row = t >> 2;        // 0..63
  const int sub = t & 3;
  const int mapA = row >> 5;     // 0 = region, 1 = affinity
  const int b = row & 31;

  float posSum = 0.f, negSum = 0.f, cntF = 0.f;
  for (int blk = sub; blk < BPS; blk += 4) {
    const float* p = part + ((size_t)b * BPS + blk) * 6 + mapA * 3;
    posSum += p[0];
    negSum += p[1];
    cntF   += p[2];
  }
#pragma unroll
  for (int msk = 1; msk <= 2; msk <<= 1) {
    posSum += __shfl_xor(posSum, msk, 64);
    negSum += __shfl_xor(negSum, msk, 64);
    cntF   += __shfl_xor(cntF, msk, 64);
  }

  __shared__ float sh[64];
  if (sub == 0) {
    const int npos = (int)cntF;           // partial counts are exact integers
    const int nneg = NPS - npos;
    long long k = 3LL * npos;
    if (k > nneg) k = nneg;

    const float thr = mapA ? THR_AFF : THR_REGION;
    const float* gt = (mapA ? ag : rg) + (size_t)b * NPS;
    const float* pd = (mapA ? ap : rp) + (size_t)b * NPS;
    const float* mm = mk + (size_t)b * NPS;

    float per_sample;
    if (npos > 0) {
      const float pos_loss = posSum / (float)npos;
      float neg_loss = 0.f;
      if (k > 0) {
        if (k == (long long)nneg) {
          neg_loss = negSum / (float)nneg;             // hot path
        } else {
          neg_loss = topk_sum_row(gt, pd, mm, thr, (int)k, true) / (float)k;
        }
      }
      per_sample = pos_loss + neg_loss;
    } else {
      per_sample = topk_sum_row(gt, pd, mm, thr, 500, false) / 500.0f;
    }
    sh[row] = per_sample;
  }
  __syncthreads();
  if (t == 0) {
    float char_sum = 0.f, affi_sum = 0.f;
    for (int i = 0; i < 32; ++i) { char_sum += sh[i]; affi_sum += sh[32 + i]; }
    out[0] = 2.0f * char_sum / (float)NB + affi_sum / (float)NB;
  }
}

extern "C" void kernel_launch(void* const* d_in, const int* in_sizes, int n_in,
                              void* d_out, int out_size, void* d_ws, size_t ws_size,
                              hipStream_t stream) {
  const float* rg = (const float*)d_in[0];
  const float* ag = (const float*)d_in[1];
  const float* rp = (const float*)d_in[2];
  const float* ap = (const float*)d_in[3];
  const float* mk = (const float*)d_in[4];
  float* out = (float*)d_out;
  float* part = (float*)d_ws;  // [NB][BPS][6] f32 = 24 KB, fully rewritten per call

  dim3 grid1(BPS, NB);
  map_loss_pass1<<<grid1, 256, 0, stream>>>(rg, ag, rp, ap, mk, part);
  map_loss_pass2<<<1, 256, 0, stream>>>(part, rg, ag, rp, ap, mk, out);
}